// Round 15
// baseline (1868.535 us; speedup 1.0000x reference)
//
#include <hip/hip_runtime.h>

// y = alpha*(x @ Q^T) + bias; alpha = mean|W|; Q = clip(round(W/alpha),-1,1)
// x:(2,4096,4096) f32, W:(16384,4096) f32, bias:(16384) f32, out f32.
#define M_DIM 8192
#define N_DIM 16384
#define K_DIM 4096
#define NT 128  // K_DIM / 32

typedef unsigned short u16;
typedef unsigned int u32;
typedef __attribute__((ext_vector_type(8))) short bf16x8;
typedef __attribute__((ext_vector_type(8))) unsigned short u16x8;
typedef __attribute__((ext_vector_type(4))) float f32x4;

#define MFMA(a, b, c) __builtin_amdgcn_mfma_f32_16x16x32_bf16(a, b, c, 0, 0, 0)
#define SGB(mask, n) __builtin_amdgcn_sched_group_barrier((mask), (n), 0)

__device__ __forceinline__ void gload16(const u16* g, u16* l) {
  __builtin_amdgcn_global_load_lds((const __attribute__((address_space(1))) void*)g,
                                   (__attribute__((address_space(3))) void*)l, 16, 0, 0);
}

// ---------------- alpha = mean(|W|), f64 two-pass reduction ----------------
__global__ void reduce_abs1(const float* __restrict__ w, double* __restrict__ partials) {
  const float4* w4 = (const float4*)w;
  size_t base = (size_t)blockIdx.x * 4096 + threadIdx.x;
  double s = 0.0;
#pragma unroll
  for (int i = 0; i < 16; ++i) {
    float4 v = w4[base + (size_t)i * 256];
    s += (double)fabsf(v.x); s += (double)fabsf(v.y);
    s += (double)fabsf(v.z); s += (double)fabsf(v.w);
  }
#pragma unroll
  for (int off = 32; off > 0; off >>= 1) s += __shfl_down(s, off, 64);
  __shared__ double red[4];
  int wv = threadIdx.x >> 6, lane = threadIdx.x & 63;
  if (lane == 0) red[wv] = s;
  __syncthreads();
  if (threadIdx.x == 0) partials[blockIdx.x] = (red[0] + red[1]) + (red[2] + red[3]);
}

__global__ void reduce_abs2(const double* __restrict__ partials,
                            double* __restrict__ alpha_d, float* __restrict__ alpha_f) {
  double s = 0.0;
  for (int i = threadIdx.x; i < 4096; i += 256) s += partials[i];
#pragma unroll
  for (int off = 32; off > 0; off >>= 1) s += __shfl_down(s, off, 64);
  __shared__ double red[4];
  int wv = threadIdx.x >> 6, lane = threadIdx.x & 63;
  if (lane == 0) red[wv] = s;
  __syncthreads();
  if (threadIdx.x == 0) {
    double total = (red[0] + red[1]) + (red[2] + red[3]);
    double a = total / (double)((long long)N_DIM * (long long)K_DIM);
    alpha_d[0] = a;
    alpha_f[0] = (float)a;
  }
}

// ---------------- W -> ternary Q stored as bf16 (+1/0/-1 exact) ----------------
__global__ void quant_w(const float* __restrict__ w, const double* __restrict__ alpha_d,
                        u16* __restrict__ q) {
  double inv = 1.0 / alpha_d[0];
  size_t i8 = (size_t)blockIdx.x * 256 + threadIdx.x;
  const float4* w4 = (const float4*)w;
  float4 v0 = w4[i8 * 2], v1 = w4[i8 * 2 + 1];
  float vv[8] = {v0.x, v0.y, v0.z, v0.w, v1.x, v1.y, v1.z, v1.w};
  u16x8 o;
#pragma unroll
  for (int j = 0; j < 8; ++j) {
    double r = rint((double)vv[j] * inv);
    u16 enc = 0;
    if (r >= 1.0) enc = 0x3F80u;
    else if (r <= -1.0) enc = 0xBF80u;
    o[j] = enc;
  }
  *((u16x8*)q + i8) = o;
}

// ---------------- x fp32 -> bf16 (RNE) ----------------
__global__ void conv_x(const float* __restrict__ x, u16* __restrict__ xb) {
  size_t i8 = (size_t)blockIdx.x * 256 + threadIdx.x;
  const float4* x4 = (const float4*)x;
  float4 v0 = x4[i8 * 2], v1 = x4[i8 * 2 + 1];
  float vv[8] = {v0.x, v0.y, v0.z, v0.w, v1.x, v1.y, v1.z, v1.w};
  u16x8 o;
#pragma unroll
  for (int j = 0; j < 8; ++j) {
    u32 u = __float_as_uint(vv[j]);
    u += 0x7FFFu + ((u >> 16) & 1u);
    o[j] = (u16)(u >> 16);
  }
  *((u16x8*)xb + i8) = o;
}

// --- 256x256-tile bf16 GEMM: FAT WAVE (128x128/wave, 1 wave/SIMD) ---
// 256 threads = 4 waves (2M x 2N); per-wave 128x128 output = acc[8][8] f32x4
// = 256 AGPR + ~100 VGPR <= 512-reg budget at 1 wave/EU (launch_bounds 256,1).
// Rationale: at wave tile 128x64 (R8-R13) the plateau is 42-50% MfmaUtil with
// LDS-read wall ~2030cy vs MFMA 2483cy per K-64. 128x128 wave tile halves
// reads/MFMA (16 reads per 64 MFMAs): LDS wall ~1000cy << MFMA wall. With
// 1 wave/SIMD there is no partner wave to hide stalls -> counted vmcnt
// (ring-4, stage g+3, wait vmcnt(16) = 2 tiles in flight stay outstanding)
// and reads issued >=1 SGB batch (~150cy MFMA) ahead cover both latencies.
// Keeps: R13 conflict-free BK=32 XOR swizzle (verified 0 conflicts), SGB
// batch interleave, XCD-bijective swizzle + supertiles (2048 % 8 == 0).
__global__ __launch_bounds__(256, 1) void gemm256(
    const u16* __restrict__ A, const u16* __restrict__ Bq,
    const float* __restrict__ bias, const float* __restrict__ alpha_f,
    float* __restrict__ C) {
  __shared__ __align__(16) u16 Alds[4][256 * 32];  // 16 KiB per ring buffer
  __shared__ __align__(16) u16 Blds[4][256 * 32];  // total 128 KiB

  const int t = threadIdx.x;
  const int wv = t >> 6, l = t & 63;
  const int wr = wv >> 1, wc = wv & 1;  // 2M x 2N wave grid
  const int lr = l & 15, lk = l >> 4;

  // XCD-bijective swizzle (2048 % 8 == 0) + 8(tm) x 64(tn) supertiles
  const int bid = blockIdx.x;
  const int wg = (bid & 7) * 256 + (bid >> 3);
  const int grp = wg >> 9, rem = wg & 511;
  const int tm = grp * 8 + (rem & 7);  // 0..31
  const int tn = rem >> 3;             // 0..63

  const u16* Ag = A + (size_t)tm * 256 * K_DIM;
  const u16* Bg = Bq + (size_t)tn * 256 * K_DIM;

  // Staging: 16B chunk q in [0,1024) of a [256][32] tile: row=q>>2, physical
  // chunk pc=q&3 holds logical c = pc ^ ((row>>1)&3) (R13-proven involution,
  // 0 conflicts). Thread t owns q = s*256 + t, s=0..3. LDS dest linear.
  int so[4], dof[4];
#pragma unroll
  for (int s = 0; s < 4; ++s) {
    int q = s * 256 + t;
    int row = q >> 2, c = (q & 3) ^ ((row >> 1) & 3);
    so[s] = row * K_DIM + c * 8;
    dof[s] = (s * 256 + wv * 64) * 8;  // u16 units (wave-uniform dest base)
  }

  // Frag read base (u16): row = sub*16 + lr, chunk lk^((lr>>1)&3);
  // sub offsets (multiples of 16 rows) fold to immediates.
  const int fb = lr * 32 + ((lk ^ ((lr >> 1) & 3)) * 8);
#define LDA(b, m) (*(const bf16x8*)(&Alds[b][wr * 4096 + (m) * 512 + fb]))
#define LDB(b, n) (*(const bf16x8*)(&Blds[b][wc * 4096 + (n) * 512 + fb]))

  f32x4 acc[8][8];
#pragma unroll
  for (int mi = 0; mi < 8; ++mi)
#pragma unroll
    for (int ni = 0; ni < 8; ++ni)
      acc[mi][ni] = (f32x4){0.f, 0.f, 0.f, 0.f};

  // stage K-tile g into ring buffer g&3 (A: 4 gloads; B: 4 gloads per thread)
  auto stageA = [&](int g) {
    if (g < NT) {
      const u16* src = Ag + g * 32;
#pragma unroll
      for (int s = 0; s < 4; ++s) gload16(src + so[s], &Alds[g & 3][dof[s]]);
    }
  };
  auto stageB = [&](int g) {
    if (g < NT) {
      const u16* src = Bg + g * 32;
#pragma unroll
      for (int s = 0; s < 4; ++s) gload16(src + so[s], &Blds[g & 3][dof[s]]);
    }
  };

  // 8 MFMAs: rows m0,m1 x cols NB..NB+3
#define M8(m0, m1, NB)                                                         \
  _Pragma("unroll") for (int n = 0; n < 4; ++n) {                              \
    acc[m0][(NB) + n] = MFMA(aF[m0], bF[(NB) + n], acc[m0][(NB) + n]);         \
    acc[m1][(NB) + n] = MFMA(aF[m1], bF[(NB) + n], acc[m1][(NB) + n]);         \
  }

  // one K-tile: 16 reads + 64 MFMAs in SGB-pinned batches; reads >=1 batch
  // ahead of first use; stages in b0/b1. b = kt&3 compile-time.
#define K_TILE(kt, b)                                                          \
  {                                                                            \
    bf16x8 aF[8], bF[8];                                                       \
    /* pre: B0-3, A0-1 */                                                      \
    bF[0] = LDB(b, 0); bF[1] = LDB(b, 1); bF[2] = LDB(b, 2); bF[3] = LDB(b, 3);\
    aF[0] = LDA(b, 0); aF[1] = LDA(b, 1);                                      \
    SGB(0x100, 6);                                                             \
    /* b0: R{A2,A3,B4,B5}; stage A(kt+3); M a0,a1 x b0-3 */                    \
    aF[2] = LDA(b, 2); aF[3] = LDA(b, 3);                                      \
    bF[4] = LDB(b, 4); bF[5] = LDB(b, 5);                                      \
    stageA((kt) + 3);                                                          \
    M8(0, 1, 0);                                                               \
    SGB(0x100, 4); SGB(0x20, 4); SGB(0x8, 8);                                  \
    /* b1: R{A4,A5,B6,B7}; stage B(kt+3); M a2,a3 x b0-3 */                    \
    aF[4] = LDA(b, 4); aF[5] = LDA(b, 5);                                      \
    bF[6] = LDB(b, 6); bF[7] = LDB(b, 7);                                      \
    stageB((kt) + 3);                                                          \
    M8(2, 3, 0);                                                               \
    SGB(0x100, 4); SGB(0x20, 4); SGB(0x8, 8);                                  \
    /* b2: R{A6,A7}; M a4,a5 x b0-3 */                                         \
    aF[6] = LDA(b, 6); aF[7] = LDA(b, 7);                                      \
    M8(4, 5, 0);                                                               \
    SGB(0x100, 2); SGB(0x8, 8);                                                \
    /* b3-b7: remaining MFMA batches */                                        \
    M8(6, 7, 0);                                                               \
    SGB(0x8, 8);                                                               \
    M8(0, 1, 4);                                                               \
    SGB(0x8, 8);                                                               \
    M8(2, 3, 4);                                                               \
    SGB(0x8, 8);                                                               \
    M8(4, 5, 4);                                                               \
    SGB(0x8, 8);                                                               \
    M8(6, 7, 4);                                                               \
    SGB(0x8, 8);                                                               \
    /* tile end: counted wait -- only tile kt+1's 8 loads must be done */      \
    if ((kt) < NT - 3) {                                                       \
      asm volatile("s_waitcnt vmcnt(16)" ::: "memory");                        \
      __builtin_amdgcn_s_barrier();                                            \
    } else if ((kt) == NT - 3) {                                               \
      asm volatile("s_waitcnt vmcnt(8)" ::: "memory");                         \
      __builtin_amdgcn_s_barrier();                                            \
    } else if ((kt) == NT - 2) {                                               \
      asm volatile("s_waitcnt vmcnt(0)" ::: "memory");                         \
      __builtin_amdgcn_s_barrier();                                            \
    } /* last tile: no wait, epilogue follows */                               \
  }

  // prologue: stage tiles 0,1,2 (24 loads); wait for tile 0's 8 (vmcnt(16))
  stageA(0); stageB(0);
  stageA(1); stageB(1);
  stageA(2); stageB(2);
  asm volatile("s_waitcnt vmcnt(16)" ::: "memory");
  __builtin_amdgcn_s_barrier();

  for (int kt4 = 0; kt4 < NT; kt4 += 4) {
    K_TILE(kt4 + 0, 0);
    K_TILE(kt4 + 1, 1);
    K_TILE(kt4 + 2, 2);
    K_TILE(kt4 + 3, 3);
  }
#undef K_TILE
#undef M8
#undef LDA
#undef LDB

  // epilogue: y = alpha*acc + bias.  C/D: col=l&15, row=4*(l>>4)+j (m89-verified)
  const float alpha = alpha_f[0];
#pragma unroll
  for (int ni = 0; ni < 8; ++ni) {
    const int col = tn * 256 + wc * 128 + ni * 16 + lr;
    const float bs = bias[col];
#pragma unroll
    for (int mi = 0; mi < 8; ++mi) {
      const int row = tm * 256 + wr * 128 + mi * 16 + lk * 4;
      float* Cp = C + (size_t)row * N_DIM + col;
#pragma unroll
      for (int j = 0; j < 4; ++j)
        Cp[(size_t)j * N_DIM] = alpha * acc[mi][ni][j] + bs;
    }
  }
}

extern "C" void kernel_launch(void* const* d_in, const int* in_sizes, int n_in,
                              void* d_out, int out_size, void* d_ws, size_t ws_size,
                              hipStream_t stream) {
  const float* x = (const float*)d_in[0];
  const float* w = (const float*)d_in[1];
  const float* bias = (const float*)d_in[2];
  float* out = (float*)d_out;

  char* ws = (char*)d_ws;
  double* alpha_d = (double*)ws;
  float* alpha_f = (float*)(ws + 8);
  double* partials = (double*)(ws + 16);
  u16* xb = (u16*)(ws + 65536);                 // 64 MiB (M*K bf16)
  u16* qb = (u16*)(ws + 65536 + 67108864ULL);   // 128 MiB (N*K bf16)

  reduce_abs1<<<4096, 256, 0, stream>>>(w, partials);
  reduce_abs2<<<1, 256, 0, stream>>>(partials, alpha_d, alpha_f);
  quant_w<<<32768, 256, 0, stream>>>(w, alpha_d, qb);
  conv_x<<<16384, 256, 0, stream>>>(x, xb);
  gemm256<<<2048, 256, 0, stream>>>(xb, qb, bias, alpha_f, out);
}

// Round 16
// 1130.477 us; speedup vs baseline: 1.6529x; 1.6529x over previous
//
#include <hip/hip_runtime.h>

// y = alpha*(x @ Q^T) + bias; alpha = mean|W|; Q = clip(round(W/alpha),-1,1)
// x:(2,4096,4096) f32, W:(16384,4096) f32, bias:(16384) f32, out f32.
#define M_DIM 8192
#define N_DIM 16384
#define K_DIM 4096
#define NT 128  // K_DIM / 32

typedef unsigned short u16;
typedef unsigned int u32;
typedef __attribute__((ext_vector_type(8))) short bf16x8;
typedef __attribute__((ext_vector_type(8))) unsigned short u16x8;
typedef __attribute__((ext_vector_type(4))) float f32x4;

#define MFMA(a, b, c) __builtin_amdgcn_mfma_f32_16x16x32_bf16(a, b, c, 0, 0, 0)
#define SGB(mask, n) __builtin_amdgcn_sched_group_barrier((mask), (n), 0)

__device__ __forceinline__ void gload16(const u16* g, u16* l) {
  __builtin_amdgcn_global_load_lds((const __attribute__((address_space(1))) void*)g,
                                   (__attribute__((address_space(3))) void*)l, 16, 0, 0);
}

// ---------------- alpha = mean(|W|), f64 two-pass reduction ----------------
__global__ void reduce_abs1(const float* __restrict__ w, double* __restrict__ partials) {
  const float4* w4 = (const float4*)w;
  size_t base = (size_t)blockIdx.x * 4096 + threadIdx.x;
  double s = 0.0;
#pragma unroll
  for (int i = 0; i < 16; ++i) {
    float4 v = w4[base + (size_t)i * 256];
    s += (double)fabsf(v.x); s += (double)fabsf(v.y);
    s += (double)fabsf(v.z); s += (double)fabsf(v.w);
  }
#pragma unroll
  for (int off = 32; off > 0; off >>= 1) s += __shfl_down(s, off, 64);
  __shared__ double red[4];
  int wv = threadIdx.x >> 6, lane = threadIdx.x & 63;
  if (lane == 0) red[wv] = s;
  __syncthreads();
  if (threadIdx.x == 0) partials[blockIdx.x] = (red[0] + red[1]) + (red[2] + red[3]);
}

__global__ void reduce_abs2(const double* __restrict__ partials,
                            double* __restrict__ alpha_d, float* __restrict__ alpha_f) {
  double s = 0.0;
  for (int i = threadIdx.x; i < 4096; i += 256) s += partials[i];
#pragma unroll
  for (int off = 32; off > 0; off >>= 1) s += __shfl_down(s, off, 64);
  __shared__ double red[4];
  int wv = threadIdx.x >> 6, lane = threadIdx.x & 63;
  if (lane == 0) red[wv] = s;
  __syncthreads();
  if (threadIdx.x == 0) {
    double total = (red[0] + red[1]) + (red[2] + red[3]);
    double a = total / (double)((long long)N_DIM * (long long)K_DIM);
    alpha_d[0] = a;
    alpha_f[0] = (float)a;
  }
}

// ---- fused prolog: W -> ternary bf16 Q  AND  x -> bf16 (one dispatch) ----
// blocks [0, 32768): quantize W (8 elems/thread); blocks [32768, 49152): cast x.
__global__ void prep_wx(const float* __restrict__ w, const float* __restrict__ x,
                        const double* __restrict__ alpha_d,
                        u16* __restrict__ q, u16* __restrict__ xb) {
  const int b = blockIdx.x;
  if (b < 32768) {
    double inv = 1.0 / alpha_d[0];
    size_t i8 = (size_t)b * 256 + threadIdx.x;
    const float4* w4 = (const float4*)w;
    float4 v0 = w4[i8 * 2], v1 = w4[i8 * 2 + 1];
    float vv[8] = {v0.x, v0.y, v0.z, v0.w, v1.x, v1.y, v1.z, v1.w};
    u16x8 o;
#pragma unroll
    for (int j = 0; j < 8; ++j) {
      double r = rint((double)vv[j] * inv);  // RNE, matches jnp.round
      u16 enc = 0;
      if (r >= 1.0) enc = 0x3F80u;            // +1.0 bf16
      else if (r <= -1.0) enc = 0xBF80u;      // -1.0 bf16
      o[j] = enc;
    }
    *((u16x8*)q + i8) = o;
  } else {
    size_t i8 = (size_t)(b - 32768) * 256 + threadIdx.x;
    const float4* x4 = (const float4*)x;
    float4 v0 = x4[i8 * 2], v1 = x4[i8 * 2 + 1];
    float vv[8] = {v0.x, v0.y, v0.z, v0.w, v1.x, v1.y, v1.z, v1.w};
    u16x8 o;
#pragma unroll
    for (int j = 0; j < 8; ++j) {
      u32 u = __float_as_uint(vv[j]);
      u += 0x7FFFu + ((u >> 16) & 1u);        // RNE f32->bf16
      o[j] = (u16)(u >> 16);
    }
    *((u16x8*)xb + i8) = o;
  }
}

// --- 256x256-tile bf16 GEMM: BK=32 ring-4, counted vmcnt, conflict-free XOR ---
// R13 verbatim (measured best: 984us GEMM, MfmaUtil 50.0%, 0 bank conflicts).
// 512 threads = 8 waves (2M x 4N); per-wave 128x64 = acc[8][4] f32x4 (128 AGPR).
// LDS: 4 ring buffers x {A 256x32, B 256x32} bf16 = 128 KiB.
// T4 counted vmcnt: tile g stages g+3 into buffer (g+3)&3; tile-end waits
// vmcnt(8) (= tile g+1's loads, issued 3 tiles earlier) -- queue never drains.
// Swizzle: c = lk ^ ((row>>1)&3) both-sides involution -> 0 conflicts (R13).
// SGB-pinned batches {<=3 ds_reads | 4 MFMAs}; no setprio (R10 -7%); no
// intra-tile barriers (R6: opposite-buffer staging never aliases current reads).
__global__ __launch_bounds__(512, 2) void gemm256(
    const u16* __restrict__ A, const u16* __restrict__ Bq,
    const float* __restrict__ bias, const float* __restrict__ alpha_f,
    float* __restrict__ C) {
  __shared__ __align__(16) u16 Alds[4][256 * 32];  // 16 KiB per ring buffer
  __shared__ __align__(16) u16 Blds[4][256 * 32];

  const int t = threadIdx.x;
  const int wv = t >> 6, l = t & 63;
  const int wr = wv >> 2, wc = wv & 3;  // 2M x 4N wave grid
  const int lr = l & 15, lk = l >> 4;

  // XCD-bijective swizzle (2048 % 8 == 0) + 8(tm) x 64(tn) supertiles
  const int bid = blockIdx.x;
  const int wg = (bid & 7) * 256 + (bid >> 3);
  const int grp = wg >> 9, rem = wg & 511;
  const int tm = grp * 8 + (rem & 7);  // 0..31
  const int tn = rem >> 3;             // 0..63

  const u16* Ag = A + (size_t)tm * 256 * K_DIM;
  const u16* Bg = Bq + (size_t)tn * 256 * K_DIM;

  // Staging: 16B chunk q in [0,1024) of a [256][32] tile: row=q>>2, physical
  // chunk pc=q&3 holds logical c = pc ^ ((row>>1)&3) (involution; read applies
  // the same XOR). LDS dest linear (wave-uniform base + lane*16).
  int so[2], dof[2];
#pragma unroll
  for (int s = 0; s < 2; ++s) {
    int q = s * 512 + t;
    int row = q >> 2, c = (q & 3) ^ ((row >> 1) & 3);
    so[s] = row * K_DIM + c * 8;
    dof[s] = (s * 512 + wv * 64) * 8;  // u16 units
  }

  // Frag read base (u16): row = sub*16 + lr, chunk lk^((lr>>1)&3);
  // per-sub offset sub*512 folds to an immediate.
  const int fb = lr * 32 + ((lk ^ ((lr >> 1) & 3)) * 8);
#define LDA(b, m) (*(const bf16x8*)(&Alds[b][wr * 4096 + (m) * 512 + fb]))
#define LDB(b, n) (*(const bf16x8*)(&Blds[b][wc * 2048 + (n) * 512 + fb]))

  f32x4 acc[8][4];
#pragma unroll
  for (int mi = 0; mi < 8; ++mi)
#pragma unroll
    for (int ni = 0; ni < 4; ++ni)
      acc[mi][ni] = (f32x4){0.f, 0.f, 0.f, 0.f};

  // stage K-tile g into ring buffer g&3 (A: 2 gloads; B: 2 gloads per thread)
  auto stageA = [&](int g) {
    if (g < NT) {
      const u16* src = Ag + g * 32;
      gload16(src + so[0], &Alds[g & 3][dof[0]]);
      gload16(src + so[1], &Alds[g & 3][dof[1]]);
    }
  };
  auto stageB = [&](int g) {
    if (g < NT) {
      const u16* src = Bg + g * 32;
      gload16(src + so[0], &Blds[g & 3][dof[0]]);
      gload16(src + so[1], &Blds[g & 3][dof[1]]);
    }
  };

#define MFMA4(m0, m1, n0, n1, aset, bset)                                      \
  acc[m0][n0] = MFMA(aset[0], bset[0], acc[m0][n0]);                           \
  acc[m0][n1] = MFMA(aset[0], bset[1], acc[m0][n1]);                           \
  acc[m1][n0] = MFMA(aset[1], bset[0], acc[m1][n0]);                           \
  acc[m1][n1] = MFMA(aset[1], bset[1], acc[m1][n1])

  // one K-tile; b = kt&3 compile-time at each expansion
#define K_TILE(kt, b)                                                          \
  {                                                                            \
    bf16x8 a01[2], a23[2], a45[2], a67[2], b01[2], b23[2];                     \
    /* pre: A0,A1,B0,B1 */                                                     \
    a01[0] = LDA(b, 0); a01[1] = LDA(b, 1);                                    \
    b01[0] = LDB(b, 0); b01[1] = LDB(b, 1);                                    \
    SGB(0x100, 4);                                                             \
    /* b0: R{A2,A3,B2}; stage A(kt+3); M{A01 x B01} */                         \
    a23[0] = LDA(b, 2); a23[1] = LDA(b, 3);                                    \
    b23[0] = LDB(b, 2);                                                        \
    stageA((kt) + 3);                                                          \
    MFMA4(0, 1, 0, 1, a01, b01);                                               \
    SGB(0x100, 3); SGB(0x20, 2); SGB(0x8, 4);                                  \
    /* b1: R{A4,A5,B3}; stage B(kt+3); M{A23 x B01} */                         \
    a45[0] = LDA(b, 4); a45[1] = LDA(b, 5);                                    \
    b23[1] = LDB(b, 3);                                                        \
    stageB((kt) + 3);                                                          \
    MFMA4(2, 3, 0, 1, a23, b01);                                               \
    SGB(0x100, 3); SGB(0x20, 2); SGB(0x8, 4);                                  \
    /* b2: R{A6,A7}; M{A01 x B23} */                                           \
    a67[0] = LDA(b, 6); a67[1] = LDA(b, 7);                                    \
    MFMA4(0, 1, 2, 3, a01, b23);                                               \
    SGB(0x100, 2); SGB(0x8, 4);                                                \
    /* b3-b7: remaining MFMA quads */                                          \
    MFMA4(2, 3, 2, 3, a23, b23);                                               \
    SGB(0x8, 4);                                                               \
    MFMA4(4, 5, 0, 1, a45, b01);                                               \
    SGB(0x8, 4);                                                               \
    MFMA4(4, 5, 2, 3, a45, b23);                                               \
    SGB(0x8, 4);                                                               \
    MFMA4(6, 7, 0, 1, a67, b01);                                               \
    SGB(0x8, 4);                                                               \
    MFMA4(6, 7, 2, 3, a67, b23);                                               \
    SGB(0x8, 4);                                                               \
    /* tile end: counted wait -- only tile kt+1's loads must be done */        \
    if ((kt) < NT - 3) {                                                       \
      asm volatile("s_waitcnt vmcnt(8)" ::: "memory");                         \
      __builtin_amdgcn_s_barrier();                                            \
    } else if ((kt) == NT - 3) {                                               \
      asm volatile("s_waitcnt vmcnt(4)" ::: "memory");                         \
      __builtin_amdgcn_s_barrier();                                            \
    } else if ((kt) == NT - 2) {                                               \
      asm volatile("s_waitcnt vmcnt(0)" ::: "memory");                         \
      __builtin_amdgcn_s_barrier();                                            \
    } /* last tile: no wait, epilogue follows */                               \
  }

  // prologue: stage tiles 0,1,2 (12 loads); wait for tile 0's 4 (vmcnt(8))
  stageA(0); stageB(0);
  stageA(1); stageB(1);
  stageA(2); stageB(2);
  asm volatile("s_waitcnt vmcnt(8)" ::: "memory");
  __builtin_amdgcn_s_barrier();

  for (int kt4 = 0; kt4 < NT; kt4 += 4) {
    K_TILE(kt4 + 0, 0);
    K_TILE(kt4 + 1, 1);
    K_TILE(kt4 + 2, 2);
    K_TILE(kt4 + 3, 3);
  }
#undef K_TILE
#undef MFMA4
#undef LDA
#undef LDB

  // epilogue: y = alpha*acc + bias.  C/D: col=l&15, row=4*(l>>4)+j (m89-verified)
  const float alpha = alpha_f[0];
#pragma unroll
  for (int ni = 0; ni < 4; ++ni) {
    const int col = tn * 256 + wc * 64 + ni * 16 + lr;
    const float bs = bias[col];
#pragma unroll
    for (int mi = 0; mi < 8; ++mi) {
      const int row = tm * 256 + wr * 128 + mi * 16 + lk * 4;
      float* Cp = C + (size_t)row * N_DIM + col;
#pragma unroll
      for (int j = 0; j < 4; ++j)
        Cp[(size_t)j * N_DIM] = alpha * acc[mi][ni][j] + bs;
    }
  }
}

extern "C" void kernel_launch(void* const* d_in, const int* in_sizes, int n_in,
                              void* d_out, int out_size, void* d_ws, size_t ws_size,
                              hipStream_t stream) {
  const float* x = (const float*)d_in[0];
  const float* w = (const float*)d_in[1];
  const float* bias = (const float*)d_in[2];
  float* out = (float*)d_out;

  char* ws = (char*)d_ws;
  double* alpha_d = (double*)ws;
  float* alpha_f = (float*)(ws + 8);
  double* partials = (double*)(ws + 16);
  u16* xb = (u16*)(ws + 65536);                 // 64 MiB (M*K bf16)
  u16* qb = (u16*)(ws + 65536 + 67108864ULL);   // 128 MiB (N*K bf16)

  reduce_abs1<<<4096, 256, 0, stream>>>(w, partials);
  reduce_abs2<<<1, 256, 0, stream>>>(partials, alpha_d, alpha_f);
  prep_wx<<<49152, 256, 0, stream>>>(w, x, alpha_d, qb, xb);
  gemm256<<<2048, 512, 0, stream>>>(xb, qb, bias, alpha_f, out);
}

// Round 17
// 789.177 us; speedup vs baseline: 2.3677x; 1.4325x over previous
//
#include <hip/hip_runtime.h>

// y = alpha*(x @ Q^T) + bias; alpha = mean|W|; Q = clip(round(W/alpha),-1,1)
// x:(2,4096,4096) f32, W:(16384,4096) f32, bias:(16384) f32, out f32.
// i8 path: Q is ternary -> i8 exact; x quantized per-row to i8 (s_m = rowmax/127);
// y = (alpha*s_m) * Sum(xq*Q) + bias with EXACT i32 MFMA accumulation.
#define M_DIM 8192
#define N_DIM 16384
#define K_DIM 4096
#define NT 64  // K_DIM / 64 (one mfma_i32_16x16x64_i8 per K-tile slice)

typedef unsigned short u16;
typedef unsigned int u32;
typedef signed char s8;
typedef __attribute__((ext_vector_type(4))) int i32x4;
typedef __attribute__((ext_vector_type(8))) signed char s8x8;
typedef __attribute__((ext_vector_type(4))) float f32x4;

#define MFMAI8(a, b, c) __builtin_amdgcn_mfma_i32_16x16x64_i8(a, b, c, 0, 0, 0)
#define SGB(mask, n) __builtin_amdgcn_sched_group_barrier((mask), (n), 0)

__device__ __forceinline__ void gload16(const void* g, void* l) {
  __builtin_amdgcn_global_load_lds((const __attribute__((address_space(1))) void*)g,
                                   (__attribute__((address_space(3))) void*)l, 16, 0, 0);
}

// ---------------- alpha = mean(|W|), f64 two-pass reduction ----------------
__global__ void reduce_abs1(const float* __restrict__ w, double* __restrict__ partials) {
  const float4* w4 = (const float4*)w;
  size_t base = (size_t)blockIdx.x * 4096 + threadIdx.x;
  double s = 0.0;
#pragma unroll
  for (int i = 0; i < 16; ++i) {
    float4 v = w4[base + (size_t)i * 256];
    s += (double)fabsf(v.x); s += (double)fabsf(v.y);
    s += (double)fabsf(v.z); s += (double)fabsf(v.w);
  }
#pragma unroll
  for (int off = 32; off > 0; off >>= 1) s += __shfl_down(s, off, 64);
  __shared__ double red[4];
  int wv = threadIdx.x >> 6, lane = threadIdx.x & 63;
  if (lane == 0) red[wv] = s;
  __syncthreads();
  if (threadIdx.x == 0) partials[blockIdx.x] = (red[0] + red[1]) + (red[2] + red[3]);
}

__global__ void reduce_abs2(const double* __restrict__ partials,
                            double* __restrict__ alpha_d, float* __restrict__ alpha_f) {
  double s = 0.0;
  for (int i = threadIdx.x; i < 4096; i += 256) s += partials[i];
#pragma unroll
  for (int off = 32; off > 0; off >>= 1) s += __shfl_down(s, off, 64);
  __shared__ double red[4];
  int wv = threadIdx.x >> 6, lane = threadIdx.x & 63;
  if (lane == 0) red[wv] = s;
  __syncthreads();
  if (threadIdx.x == 0) {
    double total = (red[0] + red[1]) + (red[2] + red[3]);
    double a = total / (double)((long long)N_DIM * (long long)K_DIM);
    alpha_d[0] = a;
    alpha_f[0] = (float)a;
  }
}

// ---- per-row x scales: sinv[m] = 127/rowmax, als[m] = alpha * rowmax/127 ----
__global__ void rowscale(const float* __restrict__ x, const float* __restrict__ alpha_f,
                         float* __restrict__ sinv, float* __restrict__ als) {
  const int row = blockIdx.x;
  const float4* x4 = (const float4*)(x + (size_t)row * K_DIM);
  float m = 0.f;
#pragma unroll
  for (int i = 0; i < 4; ++i) {
    float4 v = x4[threadIdx.x + i * 256];
    m = fmaxf(m, fmaxf(fmaxf(fabsf(v.x), fabsf(v.y)), fmaxf(fabsf(v.z), fabsf(v.w))));
  }
#pragma unroll
  for (int off = 32; off > 0; off >>= 1) m = fmaxf(m, __shfl_down(m, off, 64));
  __shared__ float red[4];
  int wv = threadIdx.x >> 6, lane = threadIdx.x & 63;
  if (lane == 0) red[wv] = m;
  __syncthreads();
  if (threadIdx.x == 0) {
    float mm = fmaxf(fmaxf(red[0], red[1]), fmaxf(red[2], red[3]));
    sinv[row] = 127.0f / mm;
    als[row] = alpha_f[0] * (mm / 127.0f);
  }
}

// ---- fused prep: W -> ternary i8 Q; x -> per-row i8 (one dispatch) ----
__global__ void prep_wx(const float* __restrict__ w, const float* __restrict__ x,
                        const double* __restrict__ alpha_d, const float* __restrict__ sinv,
                        s8* __restrict__ q, s8* __restrict__ xq) {
  const int b = blockIdx.x;
  if (b < 32768) {
    double inv = 1.0 / alpha_d[0];
    size_t i8i = (size_t)b * 256 + threadIdx.x;  // unit of 8 elems
    const float4* w4 = (const float4*)w;
    float4 v0 = w4[i8i * 2], v1 = w4[i8i * 2 + 1];
    float vv[8] = {v0.x, v0.y, v0.z, v0.w, v1.x, v1.y, v1.z, v1.w};
    s8x8 o;
#pragma unroll
    for (int j = 0; j < 8; ++j) {
      double r = rint((double)vv[j] * inv);  // RNE, matches np round
      s8 e = 0;
      if (r >= 1.0) e = 1;
      else if (r <= -1.0) e = -1;
      o[j] = e;
    }
    *((s8x8*)q + i8i) = o;
  } else {
    size_t i8i = (size_t)(b - 32768) * 256 + threadIdx.x;
    const int row = (b - 32768) >> 1;  // 2048 elems/block, 4096/row
    const float sv = sinv[row];
    const float4* x4 = (const float4*)x;
    float4 v0 = x4[i8i * 2], v1 = x4[i8i * 2 + 1];
    float vv[8] = {v0.x, v0.y, v0.z, v0.w, v1.x, v1.y, v1.z, v1.w};
    s8x8 o;
#pragma unroll
    for (int j = 0; j < 8; ++j) o[j] = (s8)(int)rintf(vv[j] * sv);  // in [-127,127]
    *((s8x8*)xq + i8i) = o;
  }
}

// --- 256x256-tile i8 GEMM: R13 skeleton byte-for-byte, i8 data, i32 acc ---
// 512 threads = 8 waves (2M x 4N); per-wave 128x64 = acc[8][4] i32x4 (128 AGPR).
// LDS: 4 ring buffers x {A 256x64B, B 256x64B} = 128 KiB -- IDENTICAL byte
// geometry to R13's bf16 [256][32] (64B rows, 4x16B chunks): the measured
// conflict-free chunk swizzle c = (q&3)^((row>>1)&3) carries over unchanged.
// K-tile = 64 i8: per wave 12 ds_reads + 32 mfma_i32_16x16x64_i8 (2x bf16
// rate, m16) -- both walls halve vs R13. T4 counted vmcnt: tile g stages g+3
// into ring (g+3)&3; tile end waits vmcnt(8) (tile g+1's 4 loads, issued 3
// tiles earlier) -- VMEM queue never drains. SGB batches; no setprio (R10);
// no intra-tile barriers (R6). XCD-bijective swizzle + supertiles.
__global__ __launch_bounds__(512, 2) void gemm_i8(
    const s8* __restrict__ A, const s8* __restrict__ Bq,
    const float* __restrict__ bias, const float* __restrict__ als,
    float* __restrict__ C) {
  __shared__ __align__(16) s8 Alds[4][256 * 64];  // 16 KiB per ring buffer
  __shared__ __align__(16) s8 Blds[4][256 * 64];

  const int t = threadIdx.x;
  const int wv = t >> 6, l = t & 63;
  const int wr = wv >> 2, wc = wv & 3;  // 2M x 4N wave grid
  const int lr = l & 15, lk = l >> 4;

  // XCD-bijective swizzle (2048 % 8 == 0) + 8(tm) x 64(tn) supertiles
  const int bid = blockIdx.x;
  const int wg = (bid & 7) * 256 + (bid >> 3);
  const int grp = wg >> 9, rem = wg & 511;
  const int tm = grp * 8 + (rem & 7);  // 0..31
  const int tn = rem >> 3;             // 0..63

  const s8* Ag = A + (size_t)tm * 256 * K_DIM;
  const s8* Bg = Bq + (size_t)tn * 256 * K_DIM;

  // Staging: 16B chunk q in [0,1024) of a [256][64B] tile: row=q>>2, physical
  // chunk pc=q&3 holds logical c = pc ^ ((row>>1)&3) (R13-proven involution,
  // 0 conflicts). LDS dest linear (wave-uniform base + lane*16). Byte units.
  int so[2], dof[2];
#pragma unroll
  for (int s = 0; s < 2; ++s) {
    int qch = s * 512 + t;
    int row = qch >> 2, c = (qch & 3) ^ ((row >> 1) & 3);
    so[s] = row * K_DIM + c * 16;
    dof[s] = (s * 512 + wv * 64) * 16;
  }

  // Frag read base (bytes): row = sub*16 + lr, chunk lk^((lr>>1)&3);
  // per-sub offset sub*1024 folds to an immediate.
  const int fb = lr * 64 + ((lk ^ ((lr >> 1) & 3)) * 16);
#define LDA(b, m) (*(const i32x4*)(&Alds[b][wr * 8192 + (m) * 1024 + fb]))
#define LDB(b, n) (*(const i32x4*)(&Blds[b][wc * 4096 + (n) * 1024 + fb]))

  i32x4 acc[8][4];
#pragma unroll
  for (int mi = 0; mi < 8; ++mi)
#pragma unroll
    for (int ni = 0; ni < 4; ++ni)
      acc[mi][ni] = (i32x4){0, 0, 0, 0};

  // stage K-tile g into ring buffer g&3 (A: 2 gloads; B: 2 gloads per thread)
  auto stageA = [&](int g) {
    if (g < NT) {
      const s8* src = Ag + g * 64;
      gload16(src + so[0], &Alds[g & 3][dof[0]]);
      gload16(src + so[1], &Alds[g & 3][dof[1]]);
    }
  };
  auto stageB = [&](int g) {
    if (g < NT) {
      const s8* src = Bg + g * 64;
      gload16(src + so[0], &Blds[g & 3][dof[0]]);
      gload16(src + so[1], &Blds[g & 3][dof[1]]);
    }
  };

#define MFMA4(m0, m1, n0, n1)                                                  \
  acc[m0][n0] = MFMAI8(aF[m0], bF[n0], acc[m0][n0]);                           \
  acc[m0][n1] = MFMAI8(aF[m0], bF[n1], acc[m0][n1]);                           \
  acc[m1][n0] = MFMAI8(aF[m1], bF[n0], acc[m1][n0]);                           \
  acc[m1][n1] = MFMAI8(aF[m1], bF[n1], acc[m1][n1])

  // one K-tile; b = kt&3 compile-time at each expansion
#define K_TILE(kt, b)                                                          \
  {                                                                            \
    i32x4 aF[8], bF[4];                                                        \
    /* pre: A0,A1,B0,B1 */                                                     \
    aF[0] = LDA(b, 0); aF[1] = LDA(b, 1);                                      \
    bF[0] = LDB(b, 0); bF[1] = LDB(b, 1);                                      \
    SGB(0x100, 4);                                                             \
    /* b0: R{A2,A3,B2}; stage A(kt+3); M{01 x 01} */                           \
    aF[2] = LDA(b, 2); aF[3] = LDA(b, 3);                                      \
    bF[2] = LDB(b, 2);                                                         \
    stageA((kt) + 3);                                                          \
    MFMA4(0, 1, 0, 1);                                                         \
    SGB(0x100, 3); SGB(0x20, 2); SGB(0x8, 4);                                  \
    /* b1: R{A4,A5,B3}; stage B(kt+3); M{23 x 01} */                           \
    aF[4] = LDA(b, 4); aF[5] = LDA(b, 5);                                      \
    bF[3] = LDB(b, 3);                                                         \
    stageB((kt) + 3);                                                          \
    MFMA4(2, 3, 0, 1);                                                         \
    SGB(0x100, 3); SGB(0x20, 2); SGB(0x8, 4);                                  \
    /* b2: R{A6,A7}; M{01 x 23} */                                             \
    aF[6] = LDA(b, 6); aF[7] = LDA(b, 7);                                      \
    MFMA4(0, 1, 2, 3);                                                         \
    SGB(0x100, 2); SGB(0x8, 4);                                                \
    /* b3-b7: remaining MFMA quads */                                          \
    MFMA4(2, 3, 2, 3);                                                         \
    SGB(0x8, 4);                                                               \
    MFMA4(4, 5, 0, 1);                                                         \
    SGB(0x8, 4);                                                               \
    MFMA4(4, 5, 2, 3);                                                         \
    SGB(0x8, 4);                                                               \
    MFMA4(6, 7, 0, 1);                                                         \
    SGB(0x8, 4);                                                               \
    MFMA4(6, 7, 2, 3);                                                         \
    SGB(0x8, 4);                                                               \
    /* tile end: counted wait -- only tile kt+1's loads must be done */        \
    if ((kt) < NT - 3) {                                                       \
      asm volatile("s_waitcnt vmcnt(8)" ::: "memory");                         \
      __builtin_amdgcn_s_barrier();                                            \
    } else if ((kt) == NT - 3) {                                               \
      asm volatile("s_waitcnt vmcnt(4)" ::: "memory");                         \
      __builtin_amdgcn_s_barrier();                                            \
    } else if ((kt) == NT - 2) {                                               \
      asm volatile("s_waitcnt vmcnt(0)" ::: "memory");                         \
      __builtin_amdgcn_s_barrier();                                            \
    } /* last tile: no wait, epilogue follows */                               \
  }

  // prologue: stage tiles 0,1,2 (12 loads); wait for tile 0's 4 (vmcnt(8))
  stageA(0); stageB(0);
  stageA(1); stageB(1);
  stageA(2); stageB(2);
  asm volatile("s_waitcnt vmcnt(8)" ::: "memory");
  __builtin_amdgcn_s_barrier();

  for (int kt4 = 0; kt4 < NT; kt4 += 4) {
    K_TILE(kt4 + 0, 0);
    K_TILE(kt4 + 1, 1);
    K_TILE(kt4 + 2, 2);
    K_TILE(kt4 + 3, 3);
  }
#undef K_TILE
#undef MFMA4
#undef LDA
#undef LDB

  // epilogue: y = als[row] * acc + bias.  C/D: col=l&15, row=4*(l>>4)+j
  // (16x16 C/D layout is dtype-independent on gfx950 -- m121/m124 i8-verified)
#pragma unroll
  for (int ni = 0; ni < 4; ++ni) {
    const int col = tn * 256 + wc * 64 + ni * 16 + lr;
    const float bs = bias[col];
#pragma unroll
    for (int mi = 0; mi < 8; ++mi) {
      const int rowbase = tm * 256 + wr * 128 + mi * 16 + lk * 4;
      const f32x4 av = *(const f32x4*)&als[rowbase];
      float* Cp = C + (size_t)rowbase * N_DIM + col;
#pragma unroll
      for (int j = 0; j < 4; ++j)
        Cp[(size_t)j * N_DIM] = av[j] * (float)acc[mi][ni][j] + bs;
    }
  }
}

extern "C" void kernel_launch(void* const* d_in, const int* in_sizes, int n_in,
                              void* d_out, int out_size, void* d_ws, size_t ws_size,
                              hipStream_t stream) {
  const float* x = (const float*)d_in[0];
  const float* w = (const float*)d_in[1];
  const float* bias = (const float*)d_in[2];
  float* out = (float*)d_out;

  char* ws = (char*)d_ws;
  double* alpha_d = (double*)ws;                    // [0,8)
  float* alpha_f = (float*)(ws + 8);                // [8,12)
  double* partials = (double*)(ws + 16);            // 32 KiB
  float* sinv = (float*)(ws + 65536);               // 32 KiB (8192 f32)
  float* als = (float*)(ws + 98304);                // 32 KiB
  s8* xq = (s8*)(ws + 131072);                      // 32 MiB (M*K i8)
  s8* qb = (s8*)(ws + 131072 + 33554432ULL);        // 64 MiB (N*K i8)
  // total ~100.8 MiB

  reduce_abs1<<<4096, 256, 0, stream>>>(w, partials);
  reduce_abs2<<<1, 256, 0, stream>>>(partials, alpha_d, alpha_f);
  rowscale<<<8192, 256, 0, stream>>>(x, alpha_f, sinv, als);
  prep_wx<<<49152, 256, 0, stream>>>(w, x, alpha_d, sinv, qb, xq);
  gemm_i8<<<2048, 512, 0, stream>>>(xq, qb, bias, als, out);
}